// Round 4
// baseline (4662.581 us; speedup 1.0000x reference)
//
#include <hip/hip_runtime.h>
#include <cstdint>

#define JAX_PARTITIONABLE 1

#define OBS_LEN 20
#define PRED_LEN 30
#define NUM_MODES 6
#define BATCH 8192
#define H 256
#define MB (NUM_MODES * BATCH) /* 49152 */

typedef __attribute__((ext_vector_type(8))) short bf16x8;
typedef __attribute__((ext_vector_type(16))) float f32x16;

// ---------------- threefry2x32 (exact JAX semantics) ----------------
__host__ __device__ inline void tf2x32(uint32_t k0, uint32_t k1, uint32_t c0, uint32_t c1,
                                       uint32_t& o0, uint32_t& o1) {
  uint32_t ks0 = k0, ks1 = k1, ks2 = k0 ^ k1 ^ 0x1BD11BDAu;
  uint32_t x0 = c0 + ks0, x1 = c1 + ks1;
#define TF_R(x, r) (((x) << (r)) | ((x) >> (32 - (r))))
#define TF_RND(r)  { x0 += x1; x1 = TF_R(x1, r); x1 ^= x0; }
  TF_RND(13) TF_RND(15) TF_RND(26) TF_RND(6)   x0 += ks1; x1 += ks2 + 1u;
  TF_RND(17) TF_RND(29) TF_RND(16) TF_RND(24)  x0 += ks2; x1 += ks0 + 2u;
  TF_RND(13) TF_RND(15) TF_RND(26) TF_RND(6)   x0 += ks0; x1 += ks1 + 3u;
  TF_RND(17) TF_RND(29) TF_RND(16) TF_RND(24)  x0 += ks1; x1 += ks2 + 4u;
  TF_RND(13) TF_RND(15) TF_RND(26) TF_RND(6)   x0 += ks2; x1 += ks0 + 5u;
  o0 = x0; o1 = x1;
#undef TF_RND
#undef TF_R
}

__device__ inline void step_key(int m, int t, uint32_t& k0, uint32_t& k1) {
#if JAX_PARTITIONABLE
  tf2x32(0u, 42u, 0u, (uint32_t)(m * PRED_LEN + t), k0, k1);
#else
  int i = m * PRED_LEN + t;
  int n0 = 2 * i, n1 = 2 * i + 1;
  uint32_t a0, a1;
  if (n0 < 180) { tf2x32(0u, 42u, (uint32_t)n0, (uint32_t)(n0 + 180), a0, a1); k0 = a0; }
  else          { tf2x32(0u, 42u, (uint32_t)(n0 - 180), (uint32_t)n0, a0, a1); k0 = a1; }
  if (n1 < 180) { tf2x32(0u, 42u, (uint32_t)n1, (uint32_t)(n1 + 180), a0, a1); k1 = a0; }
  else          { tf2x32(0u, 42u, (uint32_t)(n1 - 180), (uint32_t)n1, a0, a1); k1 = a1; }
#endif
}

__device__ inline uint32_t mask_bits(uint32_t k0, uint32_t k1, uint32_t n) {
#if JAX_PARTITIONABLE
  uint32_t o0, o1;
  tf2x32(k0, k1, 0u, n, o0, o1);
  return o0 ^ o1;
#else
  const uint32_t HALF = (uint32_t)(BATCH * 40 / 2);
  uint32_t o0, o1;
  if (n < HALF) { tf2x32(k0, k1, n, n + HALF, o0, o1); return o0; }
  else          { tf2x32(k0, k1, n - HALF, n, o0, o1); return o1; }
#endif
}

__device__ __forceinline__ float sigf(float x) { return 1.0f / (1.0f + __expf(-x)); }
__device__ __forceinline__ float tanhfast(float x) {
  float e = __expf(-2.0f * fabsf(x));
  float t = (1.0f - e) / (1.0f + e);
  return x >= 0.f ? t : -t;
}
__device__ __forceinline__ ushort f2bf(float f) {
  uint32_t u = __float_as_uint(f);
  uint32_t r = (u + 0x7fffu + ((u >> 16) & 1u)) >> 16;
  return (ushort)r;
}
__device__ __forceinline__ float bf2f(uint32_t u) { return __uint_as_float(u << 16); }

// ---------------- prep: W2 streaming layout for per-wave direct B-fragment loads ----------
// flat = ((((kt*8 + w)*4 + g)*2 + kh)*32 + n)*8 + j
// N_orig = g*256 + w*32 + n (gate g, hidden jh = w*32+n) ; k = kt*16 + kh*8 + j
__global__ __launch_bounds__(256) void k_prep(const float* __restrict__ Wih, const float* __restrict__ Whh,
                                              ushort* __restrict__ W2) {
  int idx = blockIdx.x * 256 + threadIdx.x;
  if (idx < 20 * 8 * 4 * 2 * 32 * 8) {
    int j = idx & 7, n = (idx >> 3) & 31, kh = (idx >> 8) & 1;
    int g = (idx >> 9) & 3, w = (idx >> 11) & 7, kt = idx >> 14;
    int N = g * 256 + w * 32 + n;
    int k = kt * 16 + kh * 8 + j;
    float v = (k < 40) ? Wih[N * 40 + k] : (k < 296 ? Whh[N * 256 + (k - 40)] : 0.f);
    W2[idx] = f2bf(v);
  }
}

// ---------------- fused 30-step decoder: one block = 64 rows, full recurrence ----------------
// 512 thr = 8 waves. Wave w owns gate-cols for hidden units w*32..w*32+31 (all 4 gates),
// computed via 2 rowtiles x 4 gate-ntiles of mfma_f32_32x32x16_bf16. c in registers
// (exact C-layout). h/x round-trip via LDS sA[64][328] (bf16 A rows: x(40)|h(256)|pad).
__global__ __launch_bounds__(512, 2) void k_decode(
    const float* __restrict__ traj_rel, const float* __restrict__ state_h,
    const float* __restrict__ c0, const float* __restrict__ Wse, const float* __restrict__ bse,
    const float* __restrict__ bih, const float* __restrict__ bhh,
    const ushort* __restrict__ W2, const float* __restrict__ Wp, const float* __restrict__ bp,
    float* __restrict__ rels) {
  __shared__ __align__(16) ushort sA[64][328];
  __shared__ float sWse[1600];
  __shared__ float sWp[512];
  __shared__ float sbse[40];
  __shared__ float swin[64][40];   // [row][slot*2+d] fp32 rolling window

  int tid = threadIdx.x;
  int w = tid >> 6, lane = tid & 63;
  int khl = lane >> 5, col = lane & 31;
  int blk = blockIdx.x;
  int m = blk >> 7;
  int b0 = (blk & 127) * 64;
  int jh = w * 32 + col;

  // ---- one-time init ----
  for (int i = tid; i < 1600; i += 512) sWse[i] = Wse[i];
  if (tid < 512) sWp[tid] = Wp[m * 512 + tid];
  if (tid < 40) sbse[tid] = bse[tid];
  for (int i = tid; i < 64 * 20; i += 512) {
    int row = i / 20, kk = i - row * 20;
    float2 v = *(const float2*)(traj_rel + ((size_t)kk * BATCH + b0 + row) * 2);
    swin[row][kk * 2] = v.x; swin[row][kk * 2 + 1] = v.y;
  }
  for (int i = tid; i < 64 * 256; i += 512) {
    int row = i >> 8, j = i & 255;
    sA[row][40 + j] = f2bf(state_h[((size_t)(b0 + row)) * 256 + j]);
  }
  for (int i = tid; i < 64 * 32; i += 512) {
    int row = i >> 5;
    sA[row][296 + (i & 31)] = 0;
  }
  float rbi = bih[jh] + bhh[jh];
  float rbf = bih[256 + jh] + bhh[256 + jh];
  float rbg = bih[512 + jh] + bhh[512 + jh];
  float rbo = bih[768 + jh] + bhh[768 + jh];
  float creg[2][16];
#pragma unroll
  for (int rt = 0; rt < 2; rt++)
#pragma unroll
    for (int reg = 0; reg < 16; reg++) {
      int row = rt * 32 + (reg & 3) + 8 * (reg >> 2) + 4 * khl;
      creg[rt][reg] = c0[((size_t)m * BATCH + b0 + row) * H + jh];
    }
  float bpx = bp[m * 2], bpy = bp[m * 2 + 1];
  __syncthreads();

  int q = tid & 7, prow = tid >> 3;   // pred/embed: 8 threads per row
  const int jb0 = q * 32;

#pragma unroll 1
  for (int t = 0; t < PRED_LEN; t++) {
    // ---- pred for step t-1 (h_{t-1} in sA) + window push (same-wave producer/consumer) ----
    if (t > 0) {
      float s0 = 0.f, s1 = 0.f;
#pragma unroll
      for (int p = 0; p < 4; p++) {
        uint4 hv = *(const uint4*)&sA[prow][40 + jb0 + p * 8];
        float hh[8] = {bf2f(hv.x & 0xffffu), bf2f(hv.x >> 16), bf2f(hv.y & 0xffffu), bf2f(hv.y >> 16),
                       bf2f(hv.z & 0xffffu), bf2f(hv.z >> 16), bf2f(hv.w & 0xffffu), bf2f(hv.w >> 16)};
#pragma unroll
        for (int e = 0; e < 8; e++) {
          s0 = fmaf(hh[e], sWp[jb0 + p * 8 + e], s0);
          s1 = fmaf(hh[e], sWp[256 + jb0 + p * 8 + e], s1);
        }
      }
#pragma unroll
      for (int off = 1; off < 8; off <<= 1) {
        s0 += __shfl_xor(s0, off, 64);
        s1 += __shfl_xor(s1, off, 64);
      }
      if (q == 0) {
        float rx = s0 + bpx, ry = s1 + bpy;
        *(float2*)(rels + ((size_t)(m * PRED_LEN + (t - 1)) * BATCH + b0 + prow) * 2) =
            make_float2(rx, ry);
        int slot = (t - 1) % 20;
        swin[prow][slot * 2] = rx; swin[prow][slot * 2 + 1] = ry;
      }
    }
    // ---- embed: x_j for j = q*5..q*5+4 of row prow ----
    {
      uint32_t k0, k1;
      step_key(m, t, k0, k1);
      float win[40];
#pragma unroll
      for (int kk = 0; kk < 20; kk++) {
        int idx = t + kk;
        if (idx >= 40) idx -= 40; else if (idx >= 20) idx -= 20;
        win[kk * 2] = swin[prow][idx * 2];
        win[kk * 2 + 1] = swin[prow][idx * 2 + 1];
      }
      uint32_t nb = (uint32_t)((b0 + prow) * 40 + q * 5);
#pragma unroll
      for (int jj = 0; jj < 5; jj++) {
        int j = q * 5 + jj;
        float a = sbse[j];
#pragma unroll
        for (int p = 0; p < 40; p += 4) {
          float4 wv = *(const float4*)&sWse[j * 40 + p];
          a = fmaf(win[p + 3], wv.w, fmaf(win[p + 2], wv.z, fmaf(win[p + 1], wv.y, fmaf(win[p], wv.x, a))));
        }
        a = a > 0.f ? a : 0.01f * a;
        uint32_t bits = mask_bits(k0, k1, nb + (uint32_t)jj);
        float u = __uint_as_float((bits >> 9) | 0x3f800000u) - 1.0f;
        sA[prow][j] = (u < 0.75f) ? f2bf(a * 1.3333333730697632f) : (ushort)0;
      }
    }
    __syncthreads();   // x + h ready for all waves

    // ---- GEMM: 64x320 @ 320x(w's 128 gate-cols), B-frags direct from L2, no barriers ----
    f32x16 acc[2][4];
#pragma unroll
    for (int rt = 0; rt < 2; rt++)
#pragma unroll
      for (int g = 0; g < 4; g++)
#pragma unroll
        for (int reg = 0; reg < 16; reg++) acc[rt][g][reg] = 0.f;

    const ushort* Wbase = W2 + (size_t)lane * 8;
    bf16x8 bc[4], bn[4];
#pragma unroll
    for (int g = 0; g < 4; g++) bc[g] = *(const bf16x8*)(Wbase + ((0 * 8 + w) * 4 + g) * 512);
#pragma unroll
    for (int kt = 0; kt < 20; kt++) {
      if (kt < 19) {
#pragma unroll
        for (int g = 0; g < 4; g++)
          bn[g] = *(const bf16x8*)(Wbase + (((kt + 1) * 8 + w) * 4 + g) * 512);
      }
      bf16x8 a0 = *(const bf16x8*)&sA[col][kt * 16 + khl * 8];
      bf16x8 a1 = *(const bf16x8*)&sA[32 + col][kt * 16 + khl * 8];
#pragma unroll
      for (int g = 0; g < 4; g++) {
        acc[0][g] = __builtin_amdgcn_mfma_f32_32x32x16_bf16(a0, bc[g], acc[0][g], 0, 0, 0);
        acc[1][g] = __builtin_amdgcn_mfma_f32_32x32x16_bf16(a1, bc[g], acc[1][g], 0, 0, 0);
      }
#pragma unroll
      for (int g = 0; g < 4; g++) bc[g] = bn[g];
    }
    __syncthreads();   // all waves done reading sA

    // ---- LSTM pointwise epilogue: c in regs, h -> sA (bf16) ----
#pragma unroll
    for (int rt = 0; rt < 2; rt++)
#pragma unroll
      for (int reg = 0; reg < 16; reg++) {
        int row = rt * 32 + (reg & 3) + 8 * (reg >> 2) + 4 * khl;
        float gi = acc[rt][0][reg] + rbi;
        float gf = acc[rt][1][reg] + rbf;
        float gg = acc[rt][2][reg] + rbg;
        float go = acc[rt][3][reg] + rbo;
        float c2 = sigf(gf) * creg[rt][reg] + sigf(gi) * tanhfast(gg);
        creg[rt][reg] = c2;
        sA[row][40 + jh] = f2bf(sigf(go) * tanhfast(c2));
      }
    __syncthreads();   // h visible for pred of next step
  }

  // ---- final pred: rel_29 ----
  {
    float s0 = 0.f, s1 = 0.f;
#pragma unroll
    for (int p = 0; p < 4; p++) {
      uint4 hv = *(const uint4*)&sA[prow][40 + jb0 + p * 8];
      float hh[8] = {bf2f(hv.x & 0xffffu), bf2f(hv.x >> 16), bf2f(hv.y & 0xffffu), bf2f(hv.y >> 16),
                     bf2f(hv.z & 0xffffu), bf2f(hv.z >> 16), bf2f(hv.w & 0xffffu), bf2f(hv.w >> 16)};
#pragma unroll
      for (int e = 0; e < 8; e++) {
        s0 = fmaf(hh[e], sWp[jb0 + p * 8 + e], s0);
        s1 = fmaf(hh[e], sWp[256 + jb0 + p * 8 + e], s1);
      }
    }
#pragma unroll
    for (int off = 1; off < 8; off <<= 1) {
      s0 += __shfl_xor(s0, off, 64);
      s1 += __shfl_xor(s1, off, 64);
    }
    if (q == 0) {
      *(float2*)(rels + ((size_t)(m * PRED_LEN + 29) * BATCH + b0 + prow) * 2) =
          make_float2(s0 + bpx, s1 + bpy);
    }
  }
}

// ---------------- transpose rels -> pred(B,M,T,2) + confidence net + softmax ----------------
__global__ __launch_bounds__(256) void k_transconf(const float* __restrict__ rels,
                                                   const float* __restrict__ W1, const float* __restrict__ b1,
                                                   const float* __restrict__ W2, const float* __restrict__ b2,
                                                   const float* __restrict__ wfc, const float* __restrict__ bfc,
                                                   float* __restrict__ out) {
  __shared__ float tile[32][361];
  __shared__ float sW1[3600];
  __shared__ float sW2[3600];
  __shared__ float sb1[60], sb2[60], swfc[60];
  __shared__ float sy1[192][61];
  __shared__ float slg[32][6];
  int tid = threadIdx.x;
  for (int i = tid; i < 3600; i += 256) { sW1[i] = W1[i]; sW2[i] = W2[i]; }
  if (tid < 60) { sb1[tid] = b1[tid]; sb2[tid] = b2[tid]; swfc[tid] = wfc[tid]; }
  int b0 = blockIdx.x * 32;
  for (int i = tid; i < 11520; i += 256) {
    int bl = i & 31, c = i >> 5;
    int mm = c / 60, r = c % 60;
    tile[bl][c] = rels[((size_t)((mm * PRED_LEN + (r >> 1)) * BATCH) + (b0 + bl)) * 2 + (r & 1)];
  }
  __syncthreads();
  for (int i = tid; i < 11520; i += 256) {
    int bl = i / 360, c = i % 360;
    out[(size_t)(b0 + bl) * 360 + c] = tile[bl][c];
  }
  if (tid < 192) {
    int bl = tid / 6, mm = tid - bl * 6;
    int xb = mm * 60;
    for (int qq = 0; qq < 60; qq++) {
      float acl = sb1[qq];
#pragma unroll
      for (int p = 0; p < 60; p++) acl = fmaf(tile[bl][xb + p], sW1[qq * 60 + p], acl);
      sy1[tid][qq] = fmaxf(acl, 0.f);
    }
    float logit = bfc[0];
    for (int qq = 0; qq < 60; qq++) {
      float acl = sb2[qq] + tile[bl][xb + qq];
#pragma unroll
      for (int p = 0; p < 60; p++) acl = fmaf(sy1[tid][p], sW2[qq * 60 + p], acl);
      logit = fmaf(fmaxf(acl, 0.f), swfc[qq], logit);
    }
    slg[bl][mm] = logit;
  }
  __syncthreads();
  if (tid < 32) {
    float mx = slg[tid][0];
#pragma unroll
    for (int mm = 1; mm < 6; mm++) mx = fmaxf(mx, slg[tid][mm]);
    float e[6], s = 0.f;
#pragma unroll
    for (int mm = 0; mm < 6; mm++) { e[mm] = __expf(slg[tid][mm] - mx); s += e[mm]; }
    float inv = 1.0f / s;
    size_t base = (size_t)BATCH * 360 + (size_t)(b0 + tid) * 6;
#pragma unroll
    for (int mm = 0; mm < 6; mm++) out[base + mm] = e[mm] * inv;
  }
}

// ---------------- host ----------------
extern "C" void kernel_launch(void* const* d_in, const int* in_sizes, int n_in,
                              void* d_out, int out_size, void* d_ws, size_t ws_size,
                              hipStream_t stream) {
  const float* traj_rel = (const float*)d_in[1];
  const float* state_h  = (const float*)d_in[2];
  const float* c0       = (const float*)d_in[3];
  const float* Wse      = (const float*)d_in[4];
  const float* bse      = (const float*)d_in[5];
  const float* Wih      = (const float*)d_in[6];
  const float* Whh      = (const float*)d_in[7];
  const float* bih      = (const float*)d_in[8];
  const float* bhh      = (const float*)d_in[9];
  const float* Wp       = (const float*)d_in[10];
  const float* bp       = (const float*)d_in[11];
  const float* W1       = (const float*)d_in[12];
  const float* b1       = (const float*)d_in[13];
  const float* W2c      = (const float*)d_in[14];
  const float* b2       = (const float*)d_in[15];
  const float* wfc      = (const float*)d_in[16];
  const float* bfc      = (const float*)d_in[17];
  float* out = (float*)d_out;

  float* rels = (float*)d_ws;                                     // M*T*B*2 fp32
  ushort* W2  = (ushort*)(rels + (size_t)NUM_MODES * PRED_LEN * BATCH * 2);  // 327680 bf16

  k_prep<<<1280, 256, 0, stream>>>(Wih, Whh, W2);
  k_decode<<<768, 512, 0, stream>>>(traj_rel, state_h, c0, Wse, bse, bih, bhh,
                                    W2, Wp, bp, rels);
  k_transconf<<<256, 256, 0, stream>>>(rels, W1, b1, W2c, b2, wfc, bfc, out);
}

// Round 5
// 3953.967 us; speedup vs baseline: 1.1792x; 1.1792x over previous
//
#include <hip/hip_runtime.h>
#include <cstdint>

#define JAX_PARTITIONABLE 1

#define OBS_LEN 20
#define PRED_LEN 30
#define NUM_MODES 6
#define BATCH 8192
#define H 256
#define MB (NUM_MODES * BATCH) /* 49152 */
#define SAPITCH 332            /* ushorts; 166 words = 6 mod 32 -> 2-way (free) */

typedef __attribute__((ext_vector_type(4))) short bf16x4;
typedef __attribute__((ext_vector_type(8))) short bf16x8;
typedef __attribute__((ext_vector_type(16))) float f32x16;

// ---------------- threefry2x32 (exact JAX semantics) ----------------
__host__ __device__ inline void tf2x32(uint32_t k0, uint32_t k1, uint32_t c0, uint32_t c1,
                                       uint32_t& o0, uint32_t& o1) {
  uint32_t ks0 = k0, ks1 = k1, ks2 = k0 ^ k1 ^ 0x1BD11BDAu;
  uint32_t x0 = c0 + ks0, x1 = c1 + ks1;
#define TF_R(x, r) (((x) << (r)) | ((x) >> (32 - (r))))
#define TF_RND(r)  { x0 += x1; x1 = TF_R(x1, r); x1 ^= x0; }
  TF_RND(13) TF_RND(15) TF_RND(26) TF_RND(6)   x0 += ks1; x1 += ks2 + 1u;
  TF_RND(17) TF_RND(29) TF_RND(16) TF_RND(24)  x0 += ks2; x1 += ks0 + 2u;
  TF_RND(13) TF_RND(15) TF_RND(26) TF_RND(6)   x0 += ks0; x1 += ks1 + 3u;
  TF_RND(17) TF_RND(29) TF_RND(16) TF_RND(24)  x0 += ks1; x1 += ks2 + 4u;
  TF_RND(13) TF_RND(15) TF_RND(26) TF_RND(6)   x0 += ks2; x1 += ks0 + 5u;
  o0 = x0; o1 = x1;
#undef TF_RND
#undef TF_R
}

__device__ inline void step_key(int m, int t, uint32_t& k0, uint32_t& k1) {
#if JAX_PARTITIONABLE
  tf2x32(0u, 42u, 0u, (uint32_t)(m * PRED_LEN + t), k0, k1);
#else
  int i = m * PRED_LEN + t;
  int n0 = 2 * i, n1 = 2 * i + 1;
  uint32_t a0, a1;
  if (n0 < 180) { tf2x32(0u, 42u, (uint32_t)n0, (uint32_t)(n0 + 180), a0, a1); k0 = a0; }
  else          { tf2x32(0u, 42u, (uint32_t)(n0 - 180), (uint32_t)n0, a0, a1); k0 = a1; }
  if (n1 < 180) { tf2x32(0u, 42u, (uint32_t)n1, (uint32_t)(n1 + 180), a0, a1); k1 = a0; }
  else          { tf2x32(0u, 42u, (uint32_t)(n1 - 180), (uint32_t)n1, a0, a1); k1 = a1; }
#endif
}

__device__ inline uint32_t mask_bits(uint32_t k0, uint32_t k1, uint32_t n) {
#if JAX_PARTITIONABLE
  uint32_t o0, o1;
  tf2x32(k0, k1, 0u, n, o0, o1);
  return o0 ^ o1;
#else
  const uint32_t HALF = (uint32_t)(BATCH * 40 / 2);
  uint32_t o0, o1;
  if (n < HALF) { tf2x32(k0, k1, n, n + HALF, o0, o1); return o0; }
  else          { tf2x32(k0, k1, n - HALF, n, o0, o1); return o1; }
#endif
}

__device__ __forceinline__ float sigf(float x) { return 1.0f / (1.0f + __expf(-x)); }
__device__ __forceinline__ float tanhfast(float x) {
  float e = __expf(-2.0f * fabsf(x));
  float t = (1.0f - e) / (1.0f + e);
  return x >= 0.f ? t : -t;
}
__device__ __forceinline__ ushort f2bf(float f) {
  uint32_t u = __float_as_uint(f);
  uint32_t r = (u + 0x7fffu + ((u >> 16) & 1u)) >> 16;
  return (ushort)r;
}
__device__ __forceinline__ float bf2f(uint32_t u) { return __uint_as_float(u << 16); }

// ---------------- prep: W2 wave-contiguous streaming layout ----------------
// flat = (((w*20 + kt)*4 + g)*64 + lane)*8 + j ; n = lane&31, kh = lane>>5
// N_orig = g*256 + w*32 + n ; k = kt*16 + kh*8 + j
__global__ __launch_bounds__(256) void k_prep(const float* __restrict__ Wih, const float* __restrict__ Whh,
                                              ushort* __restrict__ W2) {
  int idx = blockIdx.x * 256 + threadIdx.x;
  if (idx < 8 * 20 * 4 * 64 * 8) {
    int j = idx & 7, lane = (idx >> 3) & 63, g = (idx >> 9) & 3;
    int rest = idx >> 11;
    int kt = rest % 20, w = rest / 20;
    int n = lane & 31, kh = lane >> 5;
    int N = g * 256 + w * 32 + n;
    int k = kt * 16 + kh * 8 + j;
    float v = (k < 40) ? Wih[N * 40 + k] : (k < 296 ? Whh[N * 256 + (k - 40)] : 0.f);
    W2[idx] = f2bf(v);
  }
}

// ---------------- fused 30-step decoder: one block = 64 rows, full recurrence ----------------
__global__ __launch_bounds__(512, 1) void k_decode(
    const float* __restrict__ traj_rel, const float* __restrict__ state_h,
    const float* __restrict__ c0, const float* __restrict__ Wse, const float* __restrict__ bse,
    const float* __restrict__ bih, const float* __restrict__ bhh,
    const ushort* __restrict__ W2, const float* __restrict__ Wp, const float* __restrict__ bp,
    float* __restrict__ rels) {
  __shared__ __align__(16) ushort sA[64][SAPITCH];
  __shared__ float sWse[1600];
  __shared__ float sWp[512];
  __shared__ float sbse[40];
  __shared__ float swin[64][100];   // linear rel history: slots 0..19 = traj, 20..48 appended

  int tid = threadIdx.x;
  int w = tid >> 6, lane = tid & 63;
  int khl = lane >> 5, col = lane & 31;
  int blk = blockIdx.x;
  int m = blk >> 7;
  int b0 = (blk & 127) * 64;
  int jh = w * 32 + col;

  // ---- one-time init ----
  for (int i = tid; i < 1600; i += 512) sWse[i] = Wse[i];
  if (tid < 512) sWp[tid] = Wp[m * 512 + tid];
  if (tid < 40) sbse[tid] = bse[tid];
  for (int i = tid; i < 64 * 20; i += 512) {
    int row = i / 20, kk = i - row * 20;
    float2 v = *(const float2*)(traj_rel + ((size_t)kk * BATCH + b0 + row) * 2);
    swin[row][kk * 2] = v.x; swin[row][kk * 2 + 1] = v.y;
  }
  for (int i = tid; i < 64 * 256; i += 512) {
    int row = i >> 8, j = i & 255;
    sA[row][40 + j] = f2bf(state_h[((size_t)(b0 + row)) * 256 + j]);
  }
  for (int i = tid; i < 64 * 36; i += 512) {
    int row = i / 36;
    sA[row][296 + (i % 36)] = 0;
  }
  float rbi = bih[jh] + bhh[jh];
  float rbf = bih[256 + jh] + bhh[256 + jh];
  float rbg = bih[512 + jh] + bhh[512 + jh];
  float rbo = bih[768 + jh] + bhh[768 + jh];
  float creg[2][16];
#pragma unroll
  for (int rt = 0; rt < 2; rt++)
#pragma unroll
    for (int reg = 0; reg < 16; reg++) {
      int row = rt * 32 + (reg & 3) + 8 * (reg >> 2) + 4 * khl;
      creg[rt][reg] = c0[((size_t)m * BATCH + b0 + row) * H + jh];
    }
  float bpx = bp[m * 2], bpy = bp[m * 2 + 1];
  __syncthreads();

  int q = tid & 7, prow = tid >> 3;   // pred/embed: 8 threads per row (same wave as row)
  const int jb0 = q * 32;

#pragma unroll 1
  for (int t = 0; t < PRED_LEN; t++) {
    // ---- pred for step t-1 (h_{t-1} in sA) + history append (in-wave producer/consumer) ----
    if (t > 0) {
      float s0 = 0.f, s1 = 0.f;
#pragma unroll
      for (int p = 0; p < 8; p++) {
        uint2 hv = *(const uint2*)&sA[prow][40 + jb0 + p * 4];
        float h0 = bf2f(hv.x & 0xffffu), h1 = bf2f(hv.x >> 16);
        float h2 = bf2f(hv.y & 0xffffu), h3 = bf2f(hv.y >> 16);
        int o = jb0 + p * 4;
        s0 = fmaf(h3, sWp[o + 3], fmaf(h2, sWp[o + 2], fmaf(h1, sWp[o + 1], fmaf(h0, sWp[o], s0))));
        s1 = fmaf(h3, sWp[256 + o + 3], fmaf(h2, sWp[256 + o + 2],
             fmaf(h1, sWp[256 + o + 1], fmaf(h0, sWp[256 + o], s1))));
      }
#pragma unroll
      for (int off = 1; off < 8; off <<= 1) {
        s0 += __shfl_xor(s0, off, 64);
        s1 += __shfl_xor(s1, off, 64);
      }
      if (q == 0) {
        float rx = s0 + bpx, ry = s1 + bpy;
        *(float2*)(rels + ((size_t)(m * PRED_LEN + (t - 1)) * BATCH + b0 + prow) * 2) =
            make_float2(rx, ry);
        swin[prow][(19 + t) * 2] = rx;
        swin[prow][(19 + t) * 2 + 1] = ry;
      }
    }
    // ---- embed: x_j for j = q*5..q*5+4 of row prow; window = swin[prow][2t..2t+39] ----
    {
      uint32_t k0, k1;
      step_key(m, t, k0, k1);
      uint32_t nb = (uint32_t)((b0 + prow) * 40 + q * 5);
      const float* wrow = &swin[prow][2 * t];
#pragma unroll
      for (int jj = 0; jj < 5; jj++) {
        int j = q * 5 + jj;
        float a = sbse[j];
#pragma unroll
        for (int p = 0; p < 20; p++) {
          float2 wv = *(const float2*)(wrow + 2 * p);
          float2 we = *(const float2*)&sWse[j * 40 + 2 * p];
          a = fmaf(wv.y, we.y, fmaf(wv.x, we.x, a));
        }
        a = a > 0.f ? a : 0.01f * a;
        uint32_t bits = mask_bits(k0, k1, nb + (uint32_t)jj);
        float u = __uint_as_float((bits >> 9) | 0x3f800000u) - 1.0f;
        sA[prow][j] = (u < 0.75f) ? f2bf(a * 1.3333333730697632f) : (ushort)0;
      }
    }
    __syncthreads();   // x + h ready for all waves

    // ---- GEMM: 64x320 @ 320x(w's 128 gate-cols), B-frags streamed from L2, no barriers ----
    f32x16 acc[2][4];
#pragma unroll
    for (int rt = 0; rt < 2; rt++)
#pragma unroll
      for (int g = 0; g < 4; g++)
#pragma unroll
        for (int reg = 0; reg < 16; reg++) acc[rt][g][reg] = 0.f;

    const ushort* Wwave = W2 + (size_t)(w * 20) * 2048 + lane * 8;
    bf16x8 bc[4], bn[4];
#pragma unroll
    for (int g = 0; g < 4; g++) bc[g] = *(const bf16x8*)(Wwave + g * 512);
#pragma unroll
    for (int kt = 0; kt < 20; kt++) {
      if (kt < 19) {
#pragma unroll
        for (int g = 0; g < 4; g++)
          bn[g] = *(const bf16x8*)(Wwave + (kt + 1) * 2048 + g * 512);
      }
      const ushort* ar0 = &sA[col][kt * 16 + khl * 8];
      const ushort* ar1 = &sA[32 + col][kt * 16 + khl * 8];
      bf16x4 a0l = *(const bf16x4*)ar0;
      bf16x4 a0h = *(const bf16x4*)(ar0 + 4);
      bf16x4 a1l = *(const bf16x4*)ar1;
      bf16x4 a1h = *(const bf16x4*)(ar1 + 4);
      bf16x8 a0 = __builtin_shufflevector(a0l, a0h, 0, 1, 2, 3, 4, 5, 6, 7);
      bf16x8 a1 = __builtin_shufflevector(a1l, a1h, 0, 1, 2, 3, 4, 5, 6, 7);
#pragma unroll
      for (int g = 0; g < 4; g++) {
        acc[0][g] = __builtin_amdgcn_mfma_f32_32x32x16_bf16(a0, bc[g], acc[0][g], 0, 0, 0);
        acc[1][g] = __builtin_amdgcn_mfma_f32_32x32x16_bf16(a1, bc[g], acc[1][g], 0, 0, 0);
      }
#pragma unroll
      for (int g = 0; g < 4; g++) bc[g] = bn[g];
    }
    __syncthreads();   // all waves done reading sA

    // ---- LSTM pointwise epilogue: c in regs, h -> sA (bf16) ----
#pragma unroll
    for (int rt = 0; rt < 2; rt++)
#pragma unroll
      for (int reg = 0; reg < 16; reg++) {
        int row = rt * 32 + (reg & 3) + 8 * (reg >> 2) + 4 * khl;
        float gi = acc[rt][0][reg] + rbi;
        float gf = acc[rt][1][reg] + rbf;
        float gg = acc[rt][2][reg] + rbg;
        float go = acc[rt][3][reg] + rbo;
        float c2 = sigf(gf) * creg[rt][reg] + sigf(gi) * tanhfast(gg);
        creg[rt][reg] = c2;
        sA[row][40 + jh] = f2bf(sigf(go) * tanhfast(c2));
      }
    __syncthreads();   // h visible for pred of next step
  }

  // ---- final pred: rel_29 ----
  {
    float s0 = 0.f, s1 = 0.f;
#pragma unroll
    for (int p = 0; p < 8; p++) {
      uint2 hv = *(const uint2*)&sA[prow][40 + jb0 + p * 4];
      float h0 = bf2f(hv.x & 0xffffu), h1 = bf2f(hv.x >> 16);
      float h2 = bf2f(hv.y & 0xffffu), h3 = bf2f(hv.y >> 16);
      int o = jb0 + p * 4;
      s0 = fmaf(h3, sWp[o + 3], fmaf(h2, sWp[o + 2], fmaf(h1, sWp[o + 1], fmaf(h0, sWp[o], s0))));
      s1 = fmaf(h3, sWp[256 + o + 3], fmaf(h2, sWp[256 + o + 2],
           fmaf(h1, sWp[256 + o + 1], fmaf(h0, sWp[256 + o], s1))));
    }
#pragma unroll
    for (int off = 1; off < 8; off <<= 1) {
      s0 += __shfl_xor(s0, off, 64);
      s1 += __shfl_xor(s1, off, 64);
    }
    if (q == 0) {
      *(float2*)(rels + ((size_t)(m * PRED_LEN + 29) * BATCH + b0 + prow) * 2) =
          make_float2(s0 + bpx, s1 + bpy);
    }
  }
}

// ---------------- transpose rels -> pred(B,M,T,2) + confidence net + softmax ----------------
__global__ __launch_bounds__(256) void k_transconf(const float* __restrict__ rels,
                                                   const float* __restrict__ W1, const float* __restrict__ b1,
                                                   const float* __restrict__ W2, const float* __restrict__ b2,
                                                   const float* __restrict__ wfc, const float* __restrict__ bfc,
                                                   float* __restrict__ out) {
  __shared__ float tile[32][361];
  __shared__ float sW1[3600];
  __shared__ float sW2[3600];
  __shared__ float sb1[60], sb2[60], swfc[60];
  __shared__ float sy1[192][61];
  __shared__ float slg[32][6];
  int tid = threadIdx.x;
  for (int i = tid; i < 3600; i += 256) { sW1[i] = W1[i]; sW2[i] = W2[i]; }
  if (tid < 60) { sb1[tid] = b1[tid]; sb2[tid] = b2[tid]; swfc[tid] = wfc[tid]; }
  int b0 = blockIdx.x * 32;
  for (int i = tid; i < 11520; i += 256) {
    int bl = i & 31, c = i >> 5;
    int mm = c / 60, r = c % 60;
    tile[bl][c] = rels[((size_t)((mm * PRED_LEN + (r >> 1)) * BATCH) + (b0 + bl)) * 2 + (r & 1)];
  }
  __syncthreads();
  for (int i = tid; i < 11520; i += 256) {
    int bl = i / 360, c = i % 360;
    out[(size_t)(b0 + bl) * 360 + c] = tile[bl][c];
  }
  if (tid < 192) {
    int bl = tid / 6, mm = tid - bl * 6;
    int xb = mm * 60;
    for (int qq = 0; qq < 60; qq++) {
      float acl = sb1[qq];
#pragma unroll
      for (int p = 0; p < 60; p++) acl = fmaf(tile[bl][xb + p], sW1[qq * 60 + p], acl);
      sy1[tid][qq] = fmaxf(acl, 0.f);
    }
    float logit = bfc[0];
    for (int qq = 0; qq < 60; qq++) {
      float acl = sb2[qq] + tile[bl][xb + qq];
#pragma unroll
      for (int p = 0; p < 60; p++) acl = fmaf(sy1[tid][p], sW2[qq * 60 + p], acl);
      logit = fmaf(fmaxf(acl, 0.f), swfc[qq], logit);
    }
    slg[bl][mm] = logit;
  }
  __syncthreads();
  if (tid < 32) {
    float mx = slg[tid][0];
#pragma unroll
    for (int mm = 1; mm < 6; mm++) mx = fmaxf(mx, slg[tid][mm]);
    float e[6], s = 0.f;
#pragma unroll
    for (int mm = 0; mm < 6; mm++) { e[mm] = __expf(slg[tid][mm] - mx); s += e[mm]; }
    float inv = 1.0f / s;
    size_t base = (size_t)BATCH * 360 + (size_t)(b0 + tid) * 6;
#pragma unroll
    for (int mm = 0; mm < 6; mm++) out[base + mm] = e[mm] * inv;
  }
}

// ---------------- host ----------------
extern "C" void kernel_launch(void* const* d_in, const int* in_sizes, int n_in,
                              void* d_out, int out_size, void* d_ws, size_t ws_size,
                              hipStream_t stream) {
  const float* traj_rel = (const float*)d_in[1];
  const float* state_h  = (const float*)d_in[2];
  const float* c0       = (const float*)d_in[3];
  const float* Wse      = (const float*)d_in[4];
  const float* bse      = (const float*)d_in[5];
  const float* Wih      = (const float*)d_in[6];
  const float* Whh      = (const float*)d_in[7];
  const float* bih      = (const float*)d_in[8];
  const float* bhh      = (const float*)d_in[9];
  const float* Wp       = (const float*)d_in[10];
  const float* bp       = (const float*)d_in[11];
  const float* W1       = (const float*)d_in[12];
  const float* b1       = (const float*)d_in[13];
  const float* W2c      = (const float*)d_in[14];
  const float* b2       = (const float*)d_in[15];
  const float* wfc      = (const float*)d_in[16];
  const float* bfc      = (const float*)d_in[17];
  float* out = (float*)d_out;

  float* rels = (float*)d_ws;                                     // M*T*B*2 fp32
  ushort* W2  = (ushort*)(rels + (size_t)NUM_MODES * PRED_LEN * BATCH * 2);  // 327680 bf16

  k_prep<<<1280, 256, 0, stream>>>(Wih, Whh, W2);
  k_decode<<<768, 512, 0, stream>>>(traj_rel, state_h, c0, Wse, bse, bih, bhh,
                                    W2, Wp, bp, rels);
  k_transconf<<<256, 256, 0, stream>>>(rels, W1, b1, W2c, b2, wfc, bfc, out);
}

// Round 6
// 3538.511 us; speedup vs baseline: 1.3177x; 1.1174x over previous
//
#include <hip/hip_runtime.h>
#include <cstdint>

#define JAX_PARTITIONABLE 1

#define OBS_LEN 20
#define PRED_LEN 30
#define NUM_MODES 6
#define BATCH 8192
#define H 256
#define MB (NUM_MODES * BATCH) /* 49152 */
#define SAPITCH 332            /* ushorts; 166 words = 6 mod 32 -> 2-way (free) */

typedef __attribute__((ext_vector_type(4))) short bf16x4;
typedef __attribute__((ext_vector_type(8))) short bf16x8;
typedef __attribute__((ext_vector_type(16))) float f32x16;

// ---------------- threefry2x32 (exact JAX semantics) ----------------
__host__ __device__ inline void tf2x32(uint32_t k0, uint32_t k1, uint32_t c0, uint32_t c1,
                                       uint32_t& o0, uint32_t& o1) {
  uint32_t ks0 = k0, ks1 = k1, ks2 = k0 ^ k1 ^ 0x1BD11BDAu;
  uint32_t x0 = c0 + ks0, x1 = c1 + ks1;
#define TF_R(x, r) (((x) << (r)) | ((x) >> (32 - (r))))
#define TF_RND(r)  { x0 += x1; x1 = TF_R(x1, r); x1 ^= x0; }
  TF_RND(13) TF_RND(15) TF_RND(26) TF_RND(6)   x0 += ks1; x1 += ks2 + 1u;
  TF_RND(17) TF_RND(29) TF_RND(16) TF_RND(24)  x0 += ks2; x1 += ks0 + 2u;
  TF_RND(13) TF_RND(15) TF_RND(26) TF_RND(6)   x0 += ks0; x1 += ks1 + 3u;
  TF_RND(17) TF_RND(29) TF_RND(16) TF_RND(24)  x0 += ks1; x1 += ks2 + 4u;
  TF_RND(13) TF_RND(15) TF_RND(26) TF_RND(6)   x0 += ks2; x1 += ks0 + 5u;
  o0 = x0; o1 = x1;
#undef TF_RND
#undef TF_R
}

__device__ inline void step_key(int m, int t, uint32_t& k0, uint32_t& k1) {
#if JAX_PARTITIONABLE
  tf2x32(0u, 42u, 0u, (uint32_t)(m * PRED_LEN + t), k0, k1);
#else
  int i = m * PRED_LEN + t;
  int n0 = 2 * i, n1 = 2 * i + 1;
  uint32_t a0, a1;
  if (n0 < 180) { tf2x32(0u, 42u, (uint32_t)n0, (uint32_t)(n0 + 180), a0, a1); k0 = a0; }
  else          { tf2x32(0u, 42u, (uint32_t)(n0 - 180), (uint32_t)n0, a0, a1); k0 = a1; }
  if (n1 < 180) { tf2x32(0u, 42u, (uint32_t)n1, (uint32_t)(n1 + 180), a0, a1); k1 = a0; }
  else          { tf2x32(0u, 42u, (uint32_t)(n1 - 180), (uint32_t)n1, a0, a1); k1 = a1; }
#endif
}

__device__ inline uint32_t mask_bits(uint32_t k0, uint32_t k1, uint32_t n) {
#if JAX_PARTITIONABLE
  uint32_t o0, o1;
  tf2x32(k0, k1, 0u, n, o0, o1);
  return o0 ^ o1;
#else
  const uint32_t HALF = (uint32_t)(BATCH * 40 / 2);
  uint32_t o0, o1;
  if (n < HALF) { tf2x32(k0, k1, n, n + HALF, o0, o1); return o0; }
  else          { tf2x32(k0, k1, n - HALF, n, o0, o1); return o1; }
#endif
}

__device__ __forceinline__ float sigf(float x) { return 1.0f / (1.0f + __expf(-x)); }
__device__ __forceinline__ float tanhfast(float x) {
  float e = __expf(-2.0f * fabsf(x));
  float t = (1.0f - e) / (1.0f + e);
  return x >= 0.f ? t : -t;
}
__device__ __forceinline__ ushort f2bf(float f) {
  uint32_t u = __float_as_uint(f);
  uint32_t r = (u + 0x7fffu + ((u >> 16) & 1u)) >> 16;
  return (ushort)r;
}
__device__ __forceinline__ float bf2f(uint32_t u) { return __uint_as_float(u << 16); }

// ---------------- prep: W2 wave-contiguous streaming layout ----------------
// flat = (((w*20 + kt)*4 + g)*64 + lane)*8 + j ; n = lane&31, kh = lane>>5
// N_orig = g*256 + w*32 + n ; k = kt*16 + kh*8 + j
__global__ __launch_bounds__(256) void k_prep(const float* __restrict__ Wih, const float* __restrict__ Whh,
                                              ushort* __restrict__ W2) {
  int idx = blockIdx.x * 256 + threadIdx.x;
  if (idx < 8 * 20 * 4 * 64 * 8) {
    int j = idx & 7, lane = (idx >> 3) & 63, g = (idx >> 9) & 3;
    int rest = idx >> 11;
    int kt = rest % 20, w = rest / 20;
    int n = lane & 31, kh = lane >> 5;
    int N = g * 256 + w * 32 + n;
    int k = kt * 16 + kh * 8 + j;
    float v = (k < 40) ? Wih[N * 40 + k] : (k < 296 ? Whh[N * 256 + (k - 40)] : 0.f);
    W2[idx] = f2bf(v);
  }
}

// ---------------- fused 30-step decoder: one block = 64 rows, full recurrence ----------------
// 512 thr = 8 waves, 1 block/CU (142 KB LDS). acc (128 f32/lane) in AGPRs; c-state in LDS
// (frees 32 arch VGPRs -> no spill); W streamed from L2 with 2-deep register prefetch.
__global__ __launch_bounds__(512, 2) void k_decode(
    const float* __restrict__ traj_rel, const float* __restrict__ state_h,
    const float* __restrict__ c0, const float* __restrict__ Wse, const float* __restrict__ bse,
    const float* __restrict__ bih, const float* __restrict__ bhh,
    const ushort* __restrict__ W2, const float* __restrict__ Wp, const float* __restrict__ bp,
    float* __restrict__ rels) {
  __shared__ __align__(16) ushort sA[64][SAPITCH];  // 42496 B : x(40)|h(256)|pad, bf16
  __shared__ float sc[64][256];                     // 65536 B : fp32 c-state
  __shared__ float swin[64][100];                   // 25600 B : linear rel history
  __shared__ float sWse[1600];
  __shared__ float sWp[512];
  __shared__ float sbse[40];

  int tid = threadIdx.x;
  int w = tid >> 6, lane = tid & 63;
  int khl = lane >> 5, col = lane & 31;
  int blk = blockIdx.x;
  int m = blk >> 7;
  int b0 = (blk & 127) * 64;
  int jh = w * 32 + col;

  // ---- one-time init ----
  for (int i = tid; i < 1600; i += 512) sWse[i] = Wse[i];
  if (tid < 512) sWp[tid] = Wp[m * 512 + tid];
  if (tid < 40) sbse[tid] = bse[tid];
  for (int i = tid; i < 64 * 20; i += 512) {
    int row = i / 20, kk = i - row * 20;
    float2 v = *(const float2*)(traj_rel + ((size_t)kk * BATCH + b0 + row) * 2);
    swin[row][kk * 2] = v.x; swin[row][kk * 2 + 1] = v.y;
  }
  for (int i = tid; i < 64 * 256; i += 512) {
    int row = i >> 8, j = i & 255;
    sA[row][40 + j] = f2bf(state_h[((size_t)(b0 + row)) * 256 + j]);
  }
  for (int i = tid; i < 64 * 36; i += 512) {
    int row = i / 36;
    sA[row][296 + (i % 36)] = 0;
  }
  for (int i = tid; i < 64 * 64; i += 512) {
    int row = i >> 6, c4 = (i & 63) << 2;
    *(float4*)&sc[row][c4] = *(const float4*)(c0 + ((size_t)m * BATCH + b0 + row) * H + c4);
  }
  float rbi = bih[jh] + bhh[jh];
  float rbf = bih[256 + jh] + bhh[256 + jh];
  float rbg = bih[512 + jh] + bhh[512 + jh];
  float rbo = bih[768 + jh] + bhh[768 + jh];
  float bpx = bp[m * 2], bpy = bp[m * 2 + 1];
  __syncthreads();

  int q = tid & 7, prow = tid >> 3;   // pred/embed: 8 threads per row (same wave as row)
  const int jb0 = q * 32;

#pragma unroll 1
  for (int t = 0; t < PRED_LEN; t++) {
    // ---- pred for step t-1 (h_{t-1} in sA) + history append (in-wave producer/consumer) ----
    if (t > 0) {
      float s0 = 0.f, s1 = 0.f;
#pragma unroll
      for (int p = 0; p < 8; p++) {
        uint2 hv = *(const uint2*)&sA[prow][40 + jb0 + p * 4];
        float h0 = bf2f(hv.x & 0xffffu), h1 = bf2f(hv.x >> 16);
        float h2 = bf2f(hv.y & 0xffffu), h3 = bf2f(hv.y >> 16);
        int o = jb0 + p * 4;
        s0 = fmaf(h3, sWp[o + 3], fmaf(h2, sWp[o + 2], fmaf(h1, sWp[o + 1], fmaf(h0, sWp[o], s0))));
        s1 = fmaf(h3, sWp[256 + o + 3], fmaf(h2, sWp[256 + o + 2],
             fmaf(h1, sWp[256 + o + 1], fmaf(h0, sWp[256 + o], s1))));
      }
#pragma unroll
      for (int off = 1; off < 8; off <<= 1) {
        s0 += __shfl_xor(s0, off, 64);
        s1 += __shfl_xor(s1, off, 64);
      }
      if (q == 0) {
        float rx = s0 + bpx, ry = s1 + bpy;
        *(float2*)(rels + ((size_t)(m * PRED_LEN + (t - 1)) * BATCH + b0 + prow) * 2) =
            make_float2(rx, ry);
        swin[prow][(19 + t) * 2] = rx;
        swin[prow][(19 + t) * 2 + 1] = ry;
      }
    }
    // ---- embed: x_j for j = q*5..q*5+4 of row prow; window = swin[prow][2t..2t+39] ----
    {
      uint32_t k0, k1;
      step_key(m, t, k0, k1);
      uint32_t nb = (uint32_t)((b0 + prow) * 40 + q * 5);
      const float* wrow = &swin[prow][2 * t];
#pragma unroll
      for (int jj = 0; jj < 5; jj++) {
        int j = q * 5 + jj;
        float a = sbse[j];
#pragma unroll
        for (int p = 0; p < 20; p++) {
          float2 wv = *(const float2*)(wrow + 2 * p);
          float2 we = *(const float2*)&sWse[j * 40 + 2 * p];
          a = fmaf(wv.y, we.y, fmaf(wv.x, we.x, a));
        }
        a = a > 0.f ? a : 0.01f * a;
        uint32_t bits = mask_bits(k0, k1, nb + (uint32_t)jj);
        float u = __uint_as_float((bits >> 9) | 0x3f800000u) - 1.0f;
        sA[prow][j] = (u < 0.75f) ? f2bf(a * 1.3333333730697632f) : (ushort)0;
      }
    }
    __syncthreads();   // x + h ready for all waves

    // ---- GEMM: 64x320 @ 320x(w's 128 gate-cols); W streamed from L2, 2-deep prefetch ----
    f32x16 acc[2][4];
#pragma unroll
    for (int rt = 0; rt < 2; rt++)
#pragma unroll
      for (int g = 0; g < 4; g++)
#pragma unroll
        for (int reg = 0; reg < 16; reg++) acc[rt][g][reg] = 0.f;

    const ushort* Wwave = W2 + (size_t)(w * 20) * 2048 + lane * 8;
    bf16x8 b0f[4], b1f[4], b2f[4];
#pragma unroll
    for (int g = 0; g < 4; g++) b0f[g] = *(const bf16x8*)(Wwave + g * 512);
#pragma unroll
    for (int g = 0; g < 4; g++) b1f[g] = *(const bf16x8*)(Wwave + 2048 + g * 512);
#pragma unroll
    for (int kt = 0; kt < 20; kt++) {
      if (kt < 18) {
#pragma unroll
        for (int g = 0; g < 4; g++)
          b2f[g] = *(const bf16x8*)(Wwave + (kt + 2) * 2048 + g * 512);
      }
      const ushort* ar0 = &sA[col][kt * 16 + khl * 8];
      const ushort* ar1 = &sA[32 + col][kt * 16 + khl * 8];
      bf16x4 a0l = *(const bf16x4*)ar0;
      bf16x4 a0h = *(const bf16x4*)(ar0 + 4);
      bf16x4 a1l = *(const bf16x4*)ar1;
      bf16x4 a1h = *(const bf16x4*)(ar1 + 4);
      bf16x8 a0 = __builtin_shufflevector(a0l, a0h, 0, 1, 2, 3, 4, 5, 6, 7);
      bf16x8 a1 = __builtin_shufflevector(a1l, a1h, 0, 1, 2, 3, 4, 5, 6, 7);
#pragma unroll
      for (int g = 0; g < 4; g++) {
        acc[0][g] = __builtin_amdgcn_mfma_f32_32x32x16_bf16(a0, b0f[g], acc[0][g], 0, 0, 0);
        acc[1][g] = __builtin_amdgcn_mfma_f32_32x32x16_bf16(a1, b0f[g], acc[1][g], 0, 0, 0);
      }
#pragma unroll
      for (int g = 0; g < 4; g++) { b0f[g] = b1f[g]; b1f[g] = b2f[g]; }
    }
    __syncthreads();   // all waves done reading sA

    // ---- LSTM pointwise epilogue: c in LDS, h -> sA (bf16) ----
#pragma unroll
    for (int rt = 0; rt < 2; rt++)
#pragma unroll
      for (int reg = 0; reg < 16; reg++) {
        int row = rt * 32 + (reg & 3) + 8 * (reg >> 2) + 4 * khl;
        float gi = acc[rt][0][reg] + rbi;
        float gf = acc[rt][1][reg] + rbf;
        float gg = acc[rt][2][reg] + rbg;
        float go = acc[rt][3][reg] + rbo;
        float c2 = sigf(gf) * sc[row][jh] + sigf(gi) * tanhfast(gg);
        sc[row][jh] = c2;
        sA[row][40 + jh] = f2bf(sigf(go) * tanhfast(c2));
      }
    __syncthreads();   // h visible for pred of next step
  }

  // ---- final pred: rel_29 ----
  {
    float s0 = 0.f, s1 = 0.f;
#pragma unroll
    for (int p = 0; p < 8; p++) {
      uint2 hv = *(const uint2*)&sA[prow][40 + jb0 + p * 4];
      float h0 = bf2f(hv.x & 0xffffu), h1 = bf2f(hv.x >> 16);
      float h2 = bf2f(hv.y & 0xffffu), h3 = bf2f(hv.y >> 16);
      int o = jb0 + p * 4;
      s0 = fmaf(h3, sWp[o + 3], fmaf(h2, sWp[o + 2], fmaf(h1, sWp[o + 1], fmaf(h0, sWp[o], s0))));
      s1 = fmaf(h3, sWp[256 + o + 3], fmaf(h2, sWp[256 + o + 2],
           fmaf(h1, sWp[256 + o + 1], fmaf(h0, sWp[256 + o], s1))));
    }
#pragma unroll
    for (int off = 1; off < 8; off <<= 1) {
      s0 += __shfl_xor(s0, off, 64);
      s1 += __shfl_xor(s1, off, 64);
    }
    if (q == 0) {
      *(float2*)(rels + ((size_t)(m * PRED_LEN + 29) * BATCH + b0 + prow) * 2) =
          make_float2(s0 + bpx, s1 + bpy);
    }
  }
}

// ---------------- transpose rels -> pred(B,M,T,2) + confidence net + softmax ----------------
__global__ __launch_bounds__(256) void k_transconf(const float* __restrict__ rels,
                                                   const float* __restrict__ W1, const float* __restrict__ b1,
                                                   const float* __restrict__ W2, const float* __restrict__ b2,
                                                   const float* __restrict__ wfc, const float* __restrict__ bfc,
                                                   float* __restrict__ out) {
  __shared__ float tile[32][361];
  __shared__ float sW1[3600];
  __shared__ float sW2[3600];
  __shared__ float sb1[60], sb2[60], swfc[60];
  __shared__ float sy1[192][61];
  __shared__ float slg[32][6];
  int tid = threadIdx.x;
  for (int i = tid; i < 3600; i += 256) { sW1[i] = W1[i]; sW2[i] = W2[i]; }
  if (tid < 60) { sb1[tid] = b1[tid]; sb2[tid] = b2[tid]; swfc[tid] = wfc[tid]; }
  int b0 = blockIdx.x * 32;
  for (int i = tid; i < 11520; i += 256) {
    int bl = i & 31, c = i >> 5;
    int mm = c / 60, r = c % 60;
    tile[bl][c] = rels[((size_t)((mm * PRED_LEN + (r >> 1)) * BATCH) + (b0 + bl)) * 2 + (r & 1)];
  }
  __syncthreads();
  for (int i = tid; i < 11520; i += 256) {
    int bl = i / 360, c = i % 360;
    out[(size_t)(b0 + bl) * 360 + c] = tile[bl][c];
  }
  if (tid < 192) {
    int bl = tid / 6, mm = tid - bl * 6;
    int xb = mm * 60;
    for (int qq = 0; qq < 60; qq++) {
      float acl = sb1[qq];
#pragma unroll
      for (int p = 0; p < 60; p++) acl = fmaf(tile[bl][xb + p], sW1[qq * 60 + p], acl);
      sy1[tid][qq] = fmaxf(acl, 0.f);
    }
    float logit = bfc[0];
    for (int qq = 0; qq < 60; qq++) {
      float acl = sb2[qq] + tile[bl][xb + qq];
#pragma unroll
      for (int p = 0; p < 60; p++) acl = fmaf(sy1[tid][p], sW2[qq * 60 + p], acl);
      logit = fmaf(fmaxf(acl, 0.f), swfc[qq], logit);
    }
    slg[bl][mm] = logit;
  }
  __syncthreads();
  if (tid < 32) {
    float mx = slg[tid][0];
#pragma unroll
    for (int mm = 1; mm < 6; mm++) mx = fmaxf(mx, slg[tid][mm]);
    float e[6], s = 0.f;
#pragma unroll
    for (int mm = 0; mm < 6; mm++) { e[mm] = __expf(slg[tid][mm] - mx); s += e[mm]; }
    float inv = 1.0f / s;
    size_t base = (size_t)BATCH * 360 + (size_t)(b0 + tid) * 6;
#pragma unroll
    for (int mm = 0; mm < 6; mm++) out[base + mm] = e[mm] * inv;
  }
}

// ---------------- host ----------------
extern "C" void kernel_launch(void* const* d_in, const int* in_sizes, int n_in,
                              void* d_out, int out_size, void* d_ws, size_t ws_size,
                              hipStream_t stream) {
  const float* traj_rel = (const float*)d_in[1];
  const float* state_h  = (const float*)d_in[2];
  const float* c0       = (const float*)d_in[3];
  const float* Wse      = (const float*)d_in[4];
  const float* bse      = (const float*)d_in[5];
  const float* Wih      = (const float*)d_in[6];
  const float* Whh      = (const float*)d_in[7];
  const float* bih      = (const float*)d_in[8];
  const float* bhh      = (const float*)d_in[9];
  const float* Wp       = (const float*)d_in[10];
  const float* bp       = (const float*)d_in[11];
  const float* W1       = (const float*)d_in[12];
  const float* b1       = (const float*)d_in[13];
  const float* W2c      = (const float*)d_in[14];
  const float* b2       = (const float*)d_in[15];
  const float* wfc      = (const float*)d_in[16];
  const float* bfc      = (const float*)d_in[17];
  float* out = (float*)d_out;

  float* rels = (float*)d_ws;                                     // M*T*B*2 fp32
  ushort* W2  = (ushort*)(rels + (size_t)NUM_MODES * PRED_LEN * BATCH * 2);  // 327680 bf16

  k_prep<<<1280, 256, 0, stream>>>(Wih, Whh, W2);
  k_decode<<<768, 512, 0, stream>>>(traj_rel, state_h, c0, Wse, bse, bih, bhh,
                                    W2, Wp, bp, rels);
  k_transconf<<<256, 256, 0, stream>>>(rels, W1, b1, W2c, b2, wfc, bfc, out);
}